// Round 4
// baseline (545.387 us; speedup 1.0000x reference)
//
#include <hip/hip_runtime.h>
#include <hip/hip_fp16.h>
#include <math.h>

#define NN   50000
#define NE   1600000
#define NLBL 200000
#define CAP  80          // max in-degree+1; Poisson(32): P(deg>=80) ~ 1e-12/node
#define NEG  0.2f
#define NBK  196         // ceil(50000/256) dst buckets of 256 nodes
#define CAPB 8800        // bucket capacity: Poisson(8163) + 7 sigma
#define CHK  4096        // edges per bin block
#define GBIN 391         // (NE+CHK-1)/CHK

typedef unsigned short u16;
typedef _Float16 half8 __attribute__((ext_vector_type(8)));
typedef float floatx4 __attribute__((ext_vector_type(4)));

// ---------------- bin phase (device fn): binned counting sort, coalesced writes ----------------
// stage word: [31:24]=bucket, [23:16]=dst&255, [15:0]=src

__device__ void ph_bin(int blk, const int* __restrict__ ei,
                       int* __restrict__ gcnt, unsigned* __restrict__ bins) {
    __shared__ int cntL[NBK];
    __shared__ int offL[NBK];
    __shared__ int curL[NBK];
    __shared__ int curG[NBK];
    __shared__ unsigned stage[CHK];   // 16 KB
    const int tid = threadIdx.x;
    const int e0 = blk * CHK + tid * 16;
    const bool act = (e0 + 15) < NE;

    unsigned pk[16];
    int bb[16];
    if (act) {
#pragma unroll
        for (int g = 0; g < 4; ++g) {
            int4 s4 = *(const int4*)&ei[e0 + g * 4];
            int4 d4 = *(const int4*)&ei[NE + e0 + g * 4];
            int sa[4] = {s4.x, s4.y, s4.z, s4.w};
            int da[4] = {d4.x, d4.y, d4.z, d4.w};
#pragma unroll
            for (int k = 0; k < 4; ++k) {
                int idx = g * 4 + k;
                bb[idx] = da[k] >> 8;
                pk[idx] = (unsigned)sa[k] | ((unsigned)(da[k] & 255) << 16)
                        | ((unsigned)bb[idx] << 24);
            }
        }
    }
    for (int i = tid; i < NBK; i += 256) cntL[i] = 0;
    __syncthreads();
    if (act) {
#pragma unroll
        for (int k = 0; k < 16; ++k) atomicAdd(&cntL[bb[k]], 1);
    }
    __syncthreads();
    if (tid < NBK) {
        int acc = 0;
        for (int i = 0; i < tid; ++i) acc += cntL[i];
        offL[tid] = acc;
        curL[tid] = acc;
    }
    __syncthreads();
    for (int i = tid; i < NBK; i += 256) curG[i] = atomicAdd(&gcnt[i], cntL[i]);
    __syncthreads();
    if (act) {
#pragma unroll
        for (int k = 0; k < 16; ++k) {
            int pos = atomicAdd(&curL[bb[k]], 1);
            stage[pos] = pk[k];
        }
    }
    __syncthreads();
    const int tot = offL[NBK - 1] + cntL[NBK - 1];
    for (int j = tid; j < tot; j += 256) {
        unsigned v = stage[j];
        int b = v >> 24;
        int lr = j - offL[b];
        bins[(size_t)b * CAPB + curG[b] + lr] = v & 0x00FFFFFFu;
    }
}

__global__ __launch_bounds__(256) void k_build(const unsigned* __restrict__ bins,
                                               const int* __restrict__ gcnt,
                                               int* __restrict__ cnt,
                                               u16* __restrict__ csr) {
    __shared__ u16 rows[256 * CAP];   // 40 KB
    __shared__ int cur[256];
    const int b = blockIdx.x, tid = threadIdx.x;
    const int d0 = b << 8;
    const int nd = min(256, NN - d0);
    if (tid < nd) { cur[tid] = 1; rows[tid * CAP] = (u16)(d0 + tid); }  // self-loop slot 0
    __syncthreads();
    const int n = gcnt[b];
    for (int i = tid; i < n; i += 256) {
        unsigned v = bins[(size_t)b * CAPB + i];
        int s = v & 0xFFFF, dl = (v >> 16) & 0xFF;
        int pos = atomicAdd(&cur[dl], 1);
        if (pos < CAP) rows[dl * CAP + pos] = (u16)s;
    }
    __syncthreads();
    const unsigned* rw = (const unsigned*)rows;
    unsigned* cw = (unsigned*)(csr + (size_t)d0 * CAP);
    const int tot = nd * (CAP / 2);
    for (int i = tid; i < tot; i += 256) cw[i] = rw[i];
    if (tid < nd) cnt[d0 + tid] = cur[tid];
}

// ---------------- W -> fp16 fragment layout + gcnt zero ----------------

__global__ __launch_bounds__(256) void k_pre(const float* __restrict__ W1f,
                                             const float* __restrict__ W2f,
                                             const float* __restrict__ W3f,
                                             const float* __restrict__ W4f,
                                             half8* __restrict__ Wf1,
                                             half8* __restrict__ Wf2,
                                             half8* __restrict__ Wf3,
                                             half8* __restrict__ Wf4,
                                             int* __restrict__ gcnt) {
    if (blockIdx.x == 28) {       // folded zero
        int i = threadIdx.x;
        if (i < NBK) gcnt[i] = 0;
        return;
    }
    int e = blockIdx.x * 256 + threadIdx.x;
    const float* W;
    half8* Wf;
    int nout, le;
    if (e < 2048)      { W = W1f; Wf = Wf1; nout = 128; le = e; }
    else if (e < 4096) { W = W2f; Wf = Wf2; nout = 128; le = e - 2048; }
    else if (e < 6144) { W = W3f; Wf = Wf3; nout = 128; le = e - 4096; }
    else               { W = W4f; Wf = Wf4; nout = 64;  le = e - 6144; }
    int c = le >> 8, rem = le & 255, ks = rem >> 6, lane = rem & 63;
    int n = lane & 15, quad = lane >> 4;
    int col = c * 16 + n, k0 = ks * 32 + quad * 8;
    half8 v;
#pragma unroll
    for (int j = 0; j < 8; ++j) v[j] = (_Float16)W[(size_t)(k0 + j) * nout + col];
    Wf[le] = v;
}

// ---------------- MFMA fp16 GEMM tile: 16 rows; row-major input, PLANE output ----------------
// mfma(argA=W-frag, argB=A-frag): D[row=quad*4+reg -> w_col][col=lane&15 -> a_row].
// Output C in column-plane layout: plane p = col>>5 (32 cols, 64B rows), C[((p*NN)+row)*32 + col&31].

template <int NOUT, bool ATTN, typename TA>
__device__ __forceinline__ void gemm_tile(int gt, int lane,
                                          const TA* __restrict__ A,
                                          const half8* __restrict__ Wf,
                                          __half* __restrict__ C,
                                          const float* __restrict__ a_s,
                                          const float* __restrict__ a_d,
                                          float* __restrict__ asv,
                                          float* __restrict__ adv) {
    constexpr int CT = NOUT / 16;
    const int n = lane & 15, quad = lane >> 4;
    if (gt * 16 >= NN) return;            // 3125 tiles cover 50000 rows exactly
    const int row = gt * 16 + n;

    half8 a[4];
#pragma unroll
    for (int ks = 0; ks < 4; ++ks) {
        int c128 = ks * 32 + quad * 8;
        if constexpr (sizeof(TA) == 2) {
            a[ks] = *(const half8*)((const _Float16*)A + (size_t)row * 128 + c128);
        } else {
            const float* Ap = (const float*)A + (size_t)row * 128 + c128;
            float4 f0 = *(const float4*)Ap;
            float4 f1 = *(const float4*)(Ap + 4);
            half8 v;
            v[0] = (_Float16)f0.x; v[1] = (_Float16)f0.y; v[2] = (_Float16)f0.z; v[3] = (_Float16)f0.w;
            v[4] = (_Float16)f1.x; v[5] = (_Float16)f1.y; v[6] = (_Float16)f1.z; v[7] = (_Float16)f1.w;
            a[ks] = v;
        }
    }

    floatx4 acc[CT];
#pragma unroll
    for (int c = 0; c < CT; ++c) acc[c] = (floatx4){0.f, 0.f, 0.f, 0.f};
#pragma unroll
    for (int c = 0; c < CT; ++c) {
#pragma unroll
        for (int ks = 0; ks < 4; ++ks) {
            half8 b = Wf[(c * 4 + ks) * 64 + lane];
            acc[c] = __builtin_amdgcn_mfma_f32_16x16x32_f16(b, a[ks], acc[c], 0, 0, 0);
        }
    }

#pragma unroll
    for (int c = 0; c < CT; ++c) {
        __half2 h0 = __floats2half2_rn(acc[c][0], acc[c][1]);
        __half2 h1 = __floats2half2_rn(acc[c][2], acc[c][3]);
        uint2 u;
        __builtin_memcpy(&u.x, &h0, 4);
        __builtin_memcpy(&u.y, &h1, 4);
        int col = c * 16 + quad * 4;
        int pl = col >> 5, off = col & 31;
        *(uint2*)&C[((size_t)pl * NN + row) * 32 + off] = u;
    }

    if (ATTN) {   // fused attn dots (fp32 from acc); reduce across quads
        float ps = 0.f, pd = 0.f;
#pragma unroll
        for (int c = 0; c < CT; ++c) {
#pragma unroll
            for (int reg = 0; reg < 4; ++reg) {
                float w = acc[c][reg];
                ps = fmaf(w, a_s[c * 16 + quad * 4 + reg], ps);
                pd = fmaf(w, a_d[c * 16 + quad * 4 + reg], pd);
            }
        }
        ps += __shfl_xor(ps, 16); ps += __shfl_xor(ps, 32);
        pd += __shfl_xor(pd, 16); pd += __shfl_xor(pd, 32);
        if (quad == 0) { asv[row] = ps; adv[row] = pd; }
    }
}

// fused: blocks [0,GBIN) bin edges; blocks [GBIN, GBIN+782) run layer-1 GEMM (fp32 x input).
__global__ __launch_bounds__(256) void k_bin_gemm1(const int* __restrict__ ei,
                                                   int* __restrict__ gcnt,
                                                   unsigned* __restrict__ bins,
                                                   const float* __restrict__ x,
                                                   const half8* __restrict__ Wf1,
                                                   __half* __restrict__ G,
                                                   const float* __restrict__ a_s,
                                                   const float* __restrict__ a_d,
                                                   float* __restrict__ asv,
                                                   float* __restrict__ adv) {
    if (blockIdx.x < GBIN) { ph_bin(blockIdx.x, ei, gcnt, bins); return; }
    int gt = (blockIdx.x - GBIN) * 4 + (threadIdx.x >> 6);
    gemm_tile<128, true, float>(gt, threadIdx.x & 63, x, Wf1, G, a_s, a_d, asv, adv);
}

// standalone 64-thread GEMM kernels: 3125 one-wave blocks for load balance
template <int NOUT, bool ATTN>
__global__ __launch_bounds__(64) void k_gemm64(const __half* __restrict__ A,
                                               const half8* __restrict__ Wf,
                                               __half* __restrict__ C,
                                               const float* __restrict__ a_s,
                                               const float* __restrict__ a_d,
                                               float* __restrict__ asv,
                                               float* __restrict__ adv) {
    gemm_tile<NOUT, ATTN, __half>(blockIdx.x, threadIdx.x & 63, A, Wf, C,
                                  a_s, a_d, asv, adv);
}

// ---------------- per-dst softmax scalars: (max, 1/sum), once per layer ----------------

__global__ __launch_bounds__(256) void k_scores(const int* __restrict__ cnt,
                                                const u16* __restrict__ csr,
                                                const float* __restrict__ asv,
                                                const float* __restrict__ adv,
                                                float2* __restrict__ msv) {
    int lane = threadIdx.x & 63, wv = threadIdx.x >> 6;
    int d = blockIdx.x * 4 + wv;
    if (d >= NN) return;
    int deg = cnt[d]; if (deg > CAP) deg = CAP;
    const float advd = adv[d];
    const u16* rowp = csr + (size_t)d * CAP;
    int j0 = lane, j1 = lane + 64;
    float e0 = -INFINITY, e1 = -INFINITY;
    if (j0 < deg) {
        float t = asv[rowp[j0]] + advd;
        e0 = (t >= 0.f) ? t : NEG * t;
    }
    if (j1 < deg) {
        float t = asv[rowp[j1]] + advd;
        e1 = (t >= 0.f) ? t : NEG * t;
    }
    float m = fmaxf(e0, e1);
#pragma unroll
    for (int off = 32; off; off >>= 1) m = fmaxf(m, __shfl_xor(m, off));
    float p0 = (j0 < deg) ? __expf(e0 - m) : 0.f;
    float p1 = (j1 < deg) ? __expf(e1 - m) : 0.f;
    float s = p0 + p1;
#pragma unroll
    for (int off = 32; off; off >>= 1) s += __shfl_xor(s, off);
    if (lane == 0) msv[d] = make_float2(m, 1.f / s);
}

// fma 8 halves scaled by al into acc[0..7] (v_fma_mix-friendly form)
__device__ __forceinline__ void fma_h8v(half8 h, float al, float* acc) {
#pragma unroll
    for (int k = 0; k < 8; ++k) acc[k] = fmaf(al, (float)h[k], acc[k]);
}

// ---------------- XCD-sliced GAT aggregation ----------------
// slice = blockIdx.x & 3 -> (round-robin dispatch) slice s lives on XCDs {s, s+4};
// each XCD's L2 holds only its 3.2MB column plane -> gather misses ~compulsory.
// Wave = 1 dst x 1 slice: 16 edge-slots x 4 lanes x 8 cols, alpha from (m,inv).

__global__ __launch_bounds__(256) void k_gat_agg_sl(const __half* __restrict__ h,  // [4][NN][32]
                                                    const int* __restrict__ cnt,
                                                    const u16* __restrict__ csr,
                                                    const float* __restrict__ asv,
                                                    const float* __restrict__ adv,
                                                    const float2* __restrict__ msv,
                                                    const float* __restrict__ bias,
                                                    __half* __restrict__ out) {
    __shared__ float2 metaL[4][88];     // (alpha, src-as-bits), per wave
    int lane = threadIdx.x & 63, wv = threadIdx.x >> 6;
    int sl = blockIdx.x & 3;
    int d = (blockIdx.x >> 2) * 4 + wv;
    int deg = cnt[d]; if (deg > CAP) deg = CAP;
    const float advd = adv[d];
    const float2 mi = msv[d];
    const u16* rowp = csr + (size_t)d * CAP;

    // alpha per edge, no reduces (m, 1/sum precomputed)
    int j0 = lane, j1 = lane + 64;
    int s0 = 0, s1 = 0;
    float a0 = 0.f, a1 = 0.f;
    if (j0 < deg) {
        s0 = rowp[j0];
        float t = asv[s0] + advd;
        float e = (t >= 0.f) ? t : NEG * t;
        a0 = __expf(e - mi.x) * mi.y;
    }
    if (j1 < deg) {
        s1 = rowp[j1];
        float t = asv[s1] + advd;
        float e = (t >= 0.f) ? t : NEG * t;
        a1 = __expf(e - mi.x) * mi.y;
    }
    metaL[wv][j0] = make_float2(a0, __int_as_float(s0));
    if (j1 < 88) metaL[wv][j1] = make_float2(a1, __int_as_float(s1));

    // gather this slice's 32-col plane: 16 edge-slots x 4 lanes x 8 cols
    int slot = lane >> 2, r = lane & 3;
    const _Float16* hb = (const _Float16*)h + (size_t)sl * NN * 32 + r * 8;
    float acc[8];
#pragma unroll
    for (int k = 0; k < 8; ++k) acc[k] = 0.f;
    int degp = (deg + 15) & ~15;
    for (int base = 0; base < degp; base += 16) {
        float2 ms = metaL[wv][base + slot];
        half8 hv = *(const half8*)(hb + (size_t)__float_as_int(ms.y) * 32);
        fma_h8v(hv, ms.x, acc);
    }
#pragma unroll
    for (int k = 0; k < 8; ++k) {
        acc[k] += __shfl_xor(acc[k], 4);
        acc[k] += __shfl_xor(acc[k], 8);
        acc[k] += __shfl_xor(acc[k], 16);
        acc[k] += __shfl_xor(acc[k], 32);
    }
    if (slot == 0) {          // lanes 0..3 cover this slice's 32 cols
        int cb = sl * 32 + r * 8;
        __half2 ho[4];
#pragma unroll
        for (int k = 0; k < 4; ++k) {
            float oa = fmaxf(acc[2 * k]     + bias[cb + 2 * k],     0.f);
            float ob = fmaxf(acc[2 * k + 1] + bias[cb + 2 * k + 1], 0.f);
            ho[k] = __floats2half2_rn(oa, ob);
        }
        uint4 u;
        __builtin_memcpy(&u, &ho[0], 16);
        *(uint4*)&out[(size_t)d * 128 + cb] = u;   // row-major for the next GEMM
    }
}

// ---------------- XCD-sliced GCN aggregation (2 planes of 32 cols) ----------------

__global__ __launch_bounds__(256) void k_gcn_agg_sl(const __half* __restrict__ h,  // [2][NN][32]
                                                    const int* __restrict__ cnt,
                                                    const u16* __restrict__ csr,
                                                    const float* __restrict__ bias,
                                                    __half* __restrict__ z) {
    __shared__ float2 metaL[4][88];
    int lane = threadIdx.x & 63, wv = threadIdx.x >> 6;
    int sl = blockIdx.x & 1;
    int d = (blockIdx.x >> 1) * 4 + wv;
    int degc = cnt[d];
    int deg = degc > CAP ? CAP : degc;
    float did = rsqrtf((float)degc);
    const u16* rowp = csr + (size_t)d * CAP;

    int j0 = lane, j1 = lane + 64;
    int s0 = 0, s1 = 0;
    float n0 = 0.f, n1 = 0.f;
    if (j0 < deg) { s0 = rowp[j0]; n0 = rsqrtf((float)cnt[s0]) * did; }
    if (j1 < deg) { s1 = rowp[j1]; n1 = rsqrtf((float)cnt[s1]) * did; }
    metaL[wv][j0] = make_float2(n0, __int_as_float(s0));
    if (j1 < 88) metaL[wv][j1] = make_float2(n1, __int_as_float(s1));

    int slot = lane >> 2, r = lane & 3;
    const _Float16* hb = (const _Float16*)h + (size_t)sl * NN * 32 + r * 8;
    float acc[8];
#pragma unroll
    for (int k = 0; k < 8; ++k) acc[k] = 0.f;
    int degp = (deg + 15) & ~15;
    for (int base = 0; base < degp; base += 16) {
        float2 ms = metaL[wv][base + slot];
        half8 hv = *(const half8*)(hb + (size_t)__float_as_int(ms.y) * 32);
        fma_h8v(hv, ms.x, acc);
    }
#pragma unroll
    for (int k = 0; k < 8; ++k) {
        acc[k] += __shfl_xor(acc[k], 4);
        acc[k] += __shfl_xor(acc[k], 8);
        acc[k] += __shfl_xor(acc[k], 16);
        acc[k] += __shfl_xor(acc[k], 32);
    }
    if (slot == 0) {
        int cb = sl * 32 + r * 8;
        __half2 ho[4];
#pragma unroll
        for (int k = 0; k < 4; ++k) {
            float oa = acc[2 * k]     + bias[cb + 2 * k];
            float ob = acc[2 * k + 1] + bias[cb + 2 * k + 1];
            ho[k] = __floats2half2_rn(oa, ob);
        }
        uint4 u;
        __builtin_memcpy(&u, &ho[0], 16);
        *(uint4*)&z[(size_t)d * 64 + cb] = u;   // decode reuses z soon: keep in L2
    }
}

// ---------------- link decode (fp16 z, fp32 dot) ----------------

__global__ __launch_bounds__(256) void k_decode(const __half* __restrict__ z,
                                                const int* __restrict__ eli,
                                                float* __restrict__ outp) {
    int lane = threadIdx.x & 63, wv = threadIdx.x >> 6;
    int g = lane >> 4, r = lane & 15;
    int idx = (blockIdx.x * 4 + wv) * 4 + g;
    if (idx >= NLBL) return;
    int a = eli[idx], b = eli[NLBL + idx];
    uint2 ua = *(const uint2*)&z[(size_t)a * 64 + r * 4];
    uint2 ub = *(const uint2*)&z[(size_t)b * 64 + r * 4];
    float2 a0 = __half22float2(*(__half2*)&ua.x);
    float2 a1 = __half22float2(*(__half2*)&ua.y);
    float2 b0 = __half22float2(*(__half2*)&ub.x);
    float2 b1 = __half22float2(*(__half2*)&ub.y);
    float v = a0.x * b0.x + a0.y * b0.y + a1.x * b1.x + a1.y * b1.y;
#pragma unroll
    for (int off = 8; off; off >>= 1) v += __shfl_xor(v, off);
    if (r == 0) outp[idx] = v;
}

// ---------------- launch ----------------

extern "C" void kernel_launch(void* const* d_in, const int* in_sizes, int n_in,
                              void* d_out, int out_size, void* d_ws, size_t ws_size,
                              hipStream_t stream) {
    const float* x   = (const float*)d_in[0];
    const int*   ei  = (const int*)d_in[1];
    const int*   eli = (const int*)d_in[2];
    const float* W1 = (const float*)d_in[3];
    const float* a1s = (const float*)d_in[4];
    const float* a1d = (const float*)d_in[5];
    const float* b1 = (const float*)d_in[6];
    const float* W2 = (const float*)d_in[7];
    const float* a2s = (const float*)d_in[8];
    const float* a2d = (const float*)d_in[9];
    const float* b2 = (const float*)d_in[10];
    const float* W3 = (const float*)d_in[11];
    const float* a3s = (const float*)d_in[12];
    const float* a3d = (const float*)d_in[13];
    const float* b3 = (const float*)d_in[14];
    const float* W4 = (const float*)d_in[15];
    const float* b4 = (const float*)d_in[16];
    float* outp = (float*)d_out;

    char* p = (char*)d_ws;
    auto alloc = [&](size_t bytes) -> char* {
        char* r = p;
        p += (bytes + 255) & ~(size_t)255;
        return r;
    };
    int*    cnt  = (int*)alloc((size_t)NN * 4);
    u16*    csr  = (u16*)alloc((size_t)NN * CAP * 2);
    int*    gcnt = (int*)alloc((size_t)NBK * 4);
    float*  asvA = (float*)alloc((size_t)NN * 4);
    float*  advA = (float*)alloc((size_t)NN * 4);
    float*  asvB = (float*)alloc((size_t)NN * 4);
    float*  advB = (float*)alloc((size_t)NN * 4);
    float2* msv  = (float2*)alloc((size_t)NN * 8);
    __half* G    = (__half*)alloc((size_t)NN * 128 * 2);   // gather planes [4][NN][32]
    __half* B    = (__half*)alloc((size_t)NN * 128 * 2);   // agg output, row-major 256B rows
    __half* zf   = (__half*)alloc((size_t)NN * 64 * 2);    // gcn output
    half8*  Wf1  = (half8*)alloc(2048 * 16);
    half8*  Wf2  = (half8*)alloc(2048 * 16);
    half8*  Wf3  = (half8*)alloc(2048 * 16);
    half8*  Wf4  = (half8*)alloc(1024 * 16);
    unsigned* bins = (unsigned*)alloc((size_t)NBK * CAPB * 4);

    const int gG1   = GBIN + 782;          // bin blocks + gemm1 blocks
    const int gGemm = (NN + 15) / 16;      // 3125 one-wave blocks
    const int gSc   = (NN + 3) / 4;        // 12500 score blocks
    const int gAgg  = gSc * 4;             // 50000: 4 col-slices, slice = blockIdx & 3
    const int gGcn  = gSc * 2;             // 25000: 2 col-slices
    const int gDec  = (NLBL + 15) / 16;

    k_pre<<<29, 256, 0, stream>>>(W1, W2, W3, W4, Wf1, Wf2, Wf3, Wf4, gcnt);
    k_bin_gemm1<<<gG1, 256, 0, stream>>>(ei, gcnt, bins, x, Wf1, G, a1s, a1d, asvA, advA);
    k_build<<<NBK, 256, 0, stream>>>(bins, gcnt, cnt, csr);

    // layer 1 agg + layer 2 gemm
    k_scores<<<gSc, 256, 0, stream>>>(cnt, csr, asvA, advA, msv);
    k_gat_agg_sl<<<gAgg, 256, 0, stream>>>(G, cnt, csr, asvA, advA, msv, b1, B);
    k_gemm64<128, true><<<gGemm, 64, 0, stream>>>(B, Wf2, G, a2s, a2d, asvB, advB);

    // layer 2 agg + layer 3 gemm
    k_scores<<<gSc, 256, 0, stream>>>(cnt, csr, asvB, advB, msv);
    k_gat_agg_sl<<<gAgg, 256, 0, stream>>>(G, cnt, csr, asvB, advB, msv, b2, B);
    k_gemm64<128, true><<<gGemm, 64, 0, stream>>>(B, Wf3, G, a3s, a3d, asvA, advA);

    // layer 3 agg + layer 4 gemm (64-col, planes [2][NN][32] into G)
    k_scores<<<gSc, 256, 0, stream>>>(cnt, csr, asvA, advA, msv);
    k_gat_agg_sl<<<gAgg, 256, 0, stream>>>(G, cnt, csr, asvA, advA, msv, b3, B);
    k_gemm64<64, false><<<gGemm, 64, 0, stream>>>(B, Wf4, G, nullptr, nullptr, nullptr, nullptr);

    k_gcn_agg_sl<<<gGcn, 256, 0, stream>>>(G, cnt, csr, b4, zf);

    k_decode<<<gDec, 256, 0, stream>>>(zf, eli, outp);
}

// Round 5
// 456.778 us; speedup vs baseline: 1.1940x; 1.1940x over previous
//
#include <hip/hip_runtime.h>
#include <hip/hip_fp16.h>
#include <math.h>

#define NN   50000
#define NE   1600000
#define NLBL 200000
#define CAP  80          // max in-degree+1; Poisson(32): P(deg>=80) ~ 1e-12/node
#define NEG  0.2f
#define NBK  196         // ceil(50000/256) dst buckets of 256 nodes
#define CAPB 8800        // bucket capacity: Poisson(8163) + 7 sigma
#define CHK  4096        // edges per bin block
#define GBIN 391         // (NE+CHK-1)/CHK

typedef unsigned short u16;
typedef _Float16 half8 __attribute__((ext_vector_type(8)));
typedef float floatx4 __attribute__((ext_vector_type(4)));

// ---------------- bin phase (device fn): binned counting sort, coalesced writes ----------------
// stage word: [31:24]=bucket, [23:16]=dst&255, [15:0]=src

__device__ void ph_bin(int blk, const int* __restrict__ ei,
                       int* __restrict__ gcnt, unsigned* __restrict__ bins) {
    __shared__ int cntL[NBK];
    __shared__ int offL[NBK];
    __shared__ int curL[NBK];
    __shared__ int curG[NBK];
    __shared__ unsigned stage[CHK];   // 16 KB
    const int tid = threadIdx.x;
    const int e0 = blk * CHK + tid * 16;
    const bool act = (e0 + 15) < NE;

    unsigned pk[16];
    int bb[16];
    if (act) {
#pragma unroll
        for (int g = 0; g < 4; ++g) {
            int4 s4 = *(const int4*)&ei[e0 + g * 4];
            int4 d4 = *(const int4*)&ei[NE + e0 + g * 4];
            int sa[4] = {s4.x, s4.y, s4.z, s4.w};
            int da[4] = {d4.x, d4.y, d4.z, d4.w};
#pragma unroll
            for (int k = 0; k < 4; ++k) {
                int idx = g * 4 + k;
                bb[idx] = da[k] >> 8;
                pk[idx] = (unsigned)sa[k] | ((unsigned)(da[k] & 255) << 16)
                        | ((unsigned)bb[idx] << 24);
            }
        }
    }
    for (int i = tid; i < NBK; i += 256) cntL[i] = 0;
    __syncthreads();
    if (act) {
#pragma unroll
        for (int k = 0; k < 16; ++k) atomicAdd(&cntL[bb[k]], 1);
    }
    __syncthreads();
    if (tid < NBK) {
        int acc = 0;
        for (int i = 0; i < tid; ++i) acc += cntL[i];
        offL[tid] = acc;
        curL[tid] = acc;
    }
    __syncthreads();
    for (int i = tid; i < NBK; i += 256) curG[i] = atomicAdd(&gcnt[i], cntL[i]);
    __syncthreads();
    if (act) {
#pragma unroll
        for (int k = 0; k < 16; ++k) {
            int pos = atomicAdd(&curL[bb[k]], 1);
            stage[pos] = pk[k];
        }
    }
    __syncthreads();
    const int tot = offL[NBK - 1] + cntL[NBK - 1];
    for (int j = tid; j < tot; j += 256) {
        unsigned v = stage[j];
        int b = v >> 24;
        int lr = j - offL[b];
        bins[(size_t)b * CAPB + curG[b] + lr] = v & 0x00FFFFFFu;
    }
}

__global__ __launch_bounds__(256) void k_build(const unsigned* __restrict__ bins,
                                               const int* __restrict__ gcnt,
                                               int* __restrict__ cnt,
                                               u16* __restrict__ csr) {
    __shared__ u16 rows[256 * CAP];   // 40 KB
    __shared__ int cur[256];
    const int b = blockIdx.x, tid = threadIdx.x;
    const int d0 = b << 8;
    const int nd = min(256, NN - d0);
    if (tid < nd) { cur[tid] = 1; rows[tid * CAP] = (u16)(d0 + tid); }  // self-loop slot 0
    __syncthreads();
    const int n = gcnt[b];
    for (int i = tid; i < n; i += 256) {
        unsigned v = bins[(size_t)b * CAPB + i];
        int s = v & 0xFFFF, dl = (v >> 16) & 0xFF;
        int pos = atomicAdd(&cur[dl], 1);
        if (pos < CAP) rows[dl * CAP + pos] = (u16)s;
    }
    __syncthreads();
    const unsigned* rw = (const unsigned*)rows;
    unsigned* cw = (unsigned*)(csr + (size_t)d0 * CAP);
    const int tot = nd * (CAP / 2);
    for (int i = tid; i < tot; i += 256) cw[i] = rw[i];
    if (tid < nd) cnt[d0 + tid] = cur[tid];
}

// ---------------- W -> fp16 fragment layout + gcnt zero ----------------

__global__ __launch_bounds__(256) void k_pre(const float* __restrict__ W1f,
                                             const float* __restrict__ W2f,
                                             const float* __restrict__ W3f,
                                             const float* __restrict__ W4f,
                                             half8* __restrict__ Wf1,
                                             half8* __restrict__ Wf2,
                                             half8* __restrict__ Wf3,
                                             half8* __restrict__ Wf4,
                                             int* __restrict__ gcnt) {
    if (blockIdx.x == 28) {       // folded zero
        int i = threadIdx.x;
        if (i < NBK) gcnt[i] = 0;
        return;
    }
    int e = blockIdx.x * 256 + threadIdx.x;
    const float* W;
    half8* Wf;
    int nout, le;
    if (e < 2048)      { W = W1f; Wf = Wf1; nout = 128; le = e; }
    else if (e < 4096) { W = W2f; Wf = Wf2; nout = 128; le = e - 2048; }
    else if (e < 6144) { W = W3f; Wf = Wf3; nout = 128; le = e - 4096; }
    else               { W = W4f; Wf = Wf4; nout = 64;  le = e - 6144; }
    int c = le >> 8, rem = le & 255, ks = rem >> 6, lane = rem & 63;
    int n = lane & 15, quad = lane >> 4;
    int col = c * 16 + n, k0 = ks * 32 + quad * 8;
    half8 v;
#pragma unroll
    for (int j = 0; j < 8; ++j) v[j] = (_Float16)W[(size_t)(k0 + j) * nout + col];
    Wf[le] = v;
}

// ---------------- MFMA fp16 GEMM tile: 16 rows; row-major input, PLANE output ----------------
// mfma(argA=W-frag, argB=A-frag): D[row=quad*4+reg -> w_col][col=lane&15 -> a_row].
// Output C in column-plane layout: plane p = col>>5 (32 cols, 64B rows), C[((p*NN)+row)*32 + col&31].

template <int NOUT, bool ATTN, typename TA>
__device__ __forceinline__ void gemm_tile(int gt, int lane,
                                          const TA* __restrict__ A,
                                          const half8* __restrict__ Wf,
                                          __half* __restrict__ C,
                                          const float* __restrict__ a_s,
                                          const float* __restrict__ a_d,
                                          float* __restrict__ asv,
                                          float* __restrict__ adv) {
    constexpr int CT = NOUT / 16;
    const int n = lane & 15, quad = lane >> 4;
    if (gt * 16 >= NN) return;            // 3125 tiles cover 50000 rows exactly
    const int row = gt * 16 + n;

    half8 a[4];
#pragma unroll
    for (int ks = 0; ks < 4; ++ks) {
        int c128 = ks * 32 + quad * 8;
        if constexpr (sizeof(TA) == 2) {
            a[ks] = *(const half8*)((const _Float16*)A + (size_t)row * 128 + c128);
        } else {
            const float* Ap = (const float*)A + (size_t)row * 128 + c128;
            float4 f0 = *(const float4*)Ap;
            float4 f1 = *(const float4*)(Ap + 4);
            half8 v;
            v[0] = (_Float16)f0.x; v[1] = (_Float16)f0.y; v[2] = (_Float16)f0.z; v[3] = (_Float16)f0.w;
            v[4] = (_Float16)f1.x; v[5] = (_Float16)f1.y; v[6] = (_Float16)f1.z; v[7] = (_Float16)f1.w;
            a[ks] = v;
        }
    }

    floatx4 acc[CT];
#pragma unroll
    for (int c = 0; c < CT; ++c) acc[c] = (floatx4){0.f, 0.f, 0.f, 0.f};
#pragma unroll
    for (int c = 0; c < CT; ++c) {
#pragma unroll
        for (int ks = 0; ks < 4; ++ks) {
            half8 b = Wf[(c * 4 + ks) * 64 + lane];
            acc[c] = __builtin_amdgcn_mfma_f32_16x16x32_f16(b, a[ks], acc[c], 0, 0, 0);
        }
    }

#pragma unroll
    for (int c = 0; c < CT; ++c) {
        __half2 h0 = __floats2half2_rn(acc[c][0], acc[c][1]);
        __half2 h1 = __floats2half2_rn(acc[c][2], acc[c][3]);
        uint2 u;
        __builtin_memcpy(&u.x, &h0, 4);
        __builtin_memcpy(&u.y, &h1, 4);
        int col = c * 16 + quad * 4;
        int pl = col >> 5, off = col & 31;
        *(uint2*)&C[((size_t)pl * NN + row) * 32 + off] = u;
    }

    if (ATTN) {   // fused attn dots (fp32 from acc); reduce across quads
        float ps = 0.f, pd = 0.f;
#pragma unroll
        for (int c = 0; c < CT; ++c) {
#pragma unroll
            for (int reg = 0; reg < 4; ++reg) {
                float w = acc[c][reg];
                ps = fmaf(w, a_s[c * 16 + quad * 4 + reg], ps);
                pd = fmaf(w, a_d[c * 16 + quad * 4 + reg], pd);
            }
        }
        ps += __shfl_xor(ps, 16); ps += __shfl_xor(ps, 32);
        pd += __shfl_xor(pd, 16); pd += __shfl_xor(pd, 32);
        if (quad == 0) { asv[row] = ps; adv[row] = pd; }
    }
}

// fused: blocks [0,GBIN) bin edges; blocks [GBIN, GBIN+782) run layer-1 GEMM (fp32 x input).
__global__ __launch_bounds__(256) void k_bin_gemm1(const int* __restrict__ ei,
                                                   int* __restrict__ gcnt,
                                                   unsigned* __restrict__ bins,
                                                   const float* __restrict__ x,
                                                   const half8* __restrict__ Wf1,
                                                   __half* __restrict__ G,
                                                   const float* __restrict__ a_s,
                                                   const float* __restrict__ a_d,
                                                   float* __restrict__ asv,
                                                   float* __restrict__ adv) {
    if (blockIdx.x < GBIN) { ph_bin(blockIdx.x, ei, gcnt, bins); return; }
    int gt = (blockIdx.x - GBIN) * 4 + (threadIdx.x >> 6);
    gemm_tile<128, true, float>(gt, threadIdx.x & 63, x, Wf1, G, a_s, a_d, asv, adv);
}

// standalone 64-thread GEMM kernels: 3125 one-wave blocks for load balance
template <int NOUT, bool ATTN>
__global__ __launch_bounds__(64) void k_gemm64(const __half* __restrict__ A,
                                               const half8* __restrict__ Wf,
                                               __half* __restrict__ C,
                                               const float* __restrict__ a_s,
                                               const float* __restrict__ a_d,
                                               float* __restrict__ asv,
                                               float* __restrict__ adv) {
    gemm_tile<NOUT, ATTN, __half>(blockIdx.x, threadIdx.x & 63, A, Wf, C,
                                  a_s, a_d, asv, adv);
}

// ---------------- per-dst softmax scalars: (max, 1/sum), once per layer ----------------

__global__ __launch_bounds__(256) void k_scores(const int* __restrict__ cnt,
                                                const u16* __restrict__ csr,
                                                const float* __restrict__ asv,
                                                const float* __restrict__ adv,
                                                float2* __restrict__ msv) {
    int lane = threadIdx.x & 63, wv = threadIdx.x >> 6;
    int d = blockIdx.x * 4 + wv;
    if (d >= NN) return;
    int deg = cnt[d]; if (deg > CAP) deg = CAP;
    const float advd = adv[d];
    const u16* rowp = csr + (size_t)d * CAP;
    int j0 = lane, j1 = lane + 64;
    float e0 = -INFINITY, e1 = -INFINITY;
    if (j0 < deg) {
        float t = asv[rowp[j0]] + advd;
        e0 = (t >= 0.f) ? t : NEG * t;
    }
    if (j1 < deg) {
        float t = asv[rowp[j1]] + advd;
        e1 = (t >= 0.f) ? t : NEG * t;
    }
    float m = fmaxf(e0, e1);
#pragma unroll
    for (int off = 32; off; off >>= 1) m = fmaxf(m, __shfl_xor(m, off));
    float p0 = (j0 < deg) ? __expf(e0 - m) : 0.f;
    float p1 = (j1 < deg) ? __expf(e1 - m) : 0.f;
    float s = p0 + p1;
#pragma unroll
    for (int off = 32; off; off >>= 1) s += __shfl_xor(s, off);
    if (lane == 0) msv[d] = make_float2(m, 1.f / s);
}

// fma 8 halves scaled by al into acc[0..7] (v_fma_mix-friendly form)
__device__ __forceinline__ void fma_h8v(half8 h, float al, float* acc) {
#pragma unroll
    for (int k = 0; k < 8; ++k) acc[k] = fmaf(al, (float)h[k], acc[k]);
}

// ---------------- XCD-sliced GAT aggregation, v2 geometry ----------------
// slice = blockIdx.x & 3 (round-robin dispatch -> slice s on XCDs {s, s+4}); each
// XCD L2 holds one 3.2MB plane (FETCH floor ~43MB, measured r3).
// v2: wave = 4 dsts x 4 slots x 4 lanes x 8 cols. Fixes r3's VALU bloat:
//  - reduce: 2 shfl levels (xor 4,8) serving 4 dsts  (was 4 levels x 1 dst)
//  - alpha: 16 lanes/dst chunked over wave-max deg   (was full-wave x 1 dst)
//  - zero-padded meta -> uniform bound-free gather loop
//  - per-sub stride 84 float2 (672B = +8 banks) kills same-bank aliasing

__global__ __launch_bounds__(256) void k_gat_agg_sl(const __half* __restrict__ h,  // [4][NN][32]
                                                    const int* __restrict__ cnt,
                                                    const u16* __restrict__ csr,
                                                    const float* __restrict__ asv,
                                                    const float* __restrict__ adv,
                                                    const float2* __restrict__ msv,
                                                    const float* __restrict__ bias,
                                                    __half* __restrict__ out) {
    __shared__ float2 metaL[4][4][84];   // (alpha, src-as-bits), padded stride
    int lane = threadIdx.x & 63, wv = threadIdx.x >> 6;
    int sl = blockIdx.x & 3;
    int d0 = (blockIdx.x >> 2) * 16 + wv * 4;   // 3125 groups x 16 = NN exactly
    int sub = lane >> 4;
    int dS = d0 + sub;
    int degS = cnt[dS]; if (degS > CAP) degS = CAP;

    // zero-init this wave's meta (4*84 = 336 float2)
    float2* mw = &metaL[wv][0][0];
#pragma unroll
    for (int i = 0; i < 6; ++i) {
        int idx = i * 64 + lane;
        if (idx < 336) mw[idx] = make_float2(0.f, 0.f);
    }

    // wave-max degree -> uniform loop bounds
    int mdeg = degS;
    mdeg = max(mdeg, __shfl_xor(mdeg, 16));
    mdeg = max(mdeg, __shfl_xor(mdeg, 32));

    // ---- alpha phase: 16 lanes per dst, (m, 1/sum) precomputed by k_scores ----
    const float advd = adv[dS];
    const float2 mi = msv[dS];
    const u16* rowp = csr + (size_t)dS * CAP;
    int jj = lane & 15;
    for (int j = jj; j < mdeg; j += 16) {
        int s = rowp[j];                          // row is CAP-allocated: safe
        float t = asv[s] + advd;
        float e = (t >= 0.f) ? t : NEG * t;
        float al = __expf(e - mi.x) * mi.y;
        bool ok = j < degS;
        metaL[wv][sub][j] = make_float2(ok ? al : 0.f, __int_as_float(ok ? s : 0));
    }

    // ---- gather loop: 4 slots x 4 lanes x 8 cols on this slice's plane ----
    int slot = (lane >> 2) & 3, r = lane & 3;
    const _Float16* plane = (const _Float16*)h + (size_t)sl * NN * 32;
    float acc[8];
#pragma unroll
    for (int k = 0; k < 8; ++k) acc[k] = 0.f;
    int trips = (mdeg + 3) >> 2;
    const float2* mrow = &metaL[wv][sub][0];
    for (int t = 0; t < trips; ++t) {
        float2 ms = mrow[t * 4 + slot];
        int sj = __float_as_int(ms.y);
        half8 hv = *(const half8*)(plane + (((sj << 2) + r) << 3));
        fma_h8v(hv, ms.x, acc);                   // alpha==0 pads are exact no-ops
    }
#pragma unroll
    for (int k = 0; k < 8; ++k) {
        acc[k] += __shfl_xor(acc[k], 4);
        acc[k] += __shfl_xor(acc[k], 8);
    }
    if ((lane & 12) == 0) {    // slot 0: 4 lanes cover this slice's 32 cols
        int cb = sl * 32 + r * 8;
        __half2 ho[4];
#pragma unroll
        for (int k = 0; k < 4; ++k) {
            float oa = fmaxf(acc[2 * k]     + bias[cb + 2 * k],     0.f);
            float ob = fmaxf(acc[2 * k + 1] + bias[cb + 2 * k + 1], 0.f);
            ho[k] = __floats2half2_rn(oa, ob);
        }
        uint4 u;
        __builtin_memcpy(&u, &ho[0], 16);
        *(uint4*)&out[(size_t)dS * 128 + cb] = u;   // row-major for the next GEMM
    }
}

// ---------------- XCD-sliced GCN aggregation, v2 geometry (2 planes of 32 cols) ----------------

__global__ __launch_bounds__(256) void k_gcn_agg_sl(const __half* __restrict__ h,  // [2][NN][32]
                                                    const int* __restrict__ cnt,
                                                    const u16* __restrict__ csr,
                                                    const float* __restrict__ bias,
                                                    __half* __restrict__ z) {
    __shared__ float2 metaL[4][4][84];
    int lane = threadIdx.x & 63, wv = threadIdx.x >> 6;
    int sl = blockIdx.x & 1;
    int d0 = (blockIdx.x >> 1) * 16 + wv * 4;   // 3125 groups x 16 = NN exactly
    int sub = lane >> 4;
    int dS = d0 + sub;
    int degc = cnt[dS];
    int degS = degc > CAP ? CAP : degc;

    float2* mw = &metaL[wv][0][0];
#pragma unroll
    for (int i = 0; i < 6; ++i) {
        int idx = i * 64 + lane;
        if (idx < 336) mw[idx] = make_float2(0.f, 0.f);
    }

    int mdeg = degS;
    mdeg = max(mdeg, __shfl_xor(mdeg, 16));
    mdeg = max(mdeg, __shfl_xor(mdeg, 32));

    float did = rsqrtf((float)degc);
    const u16* rowp = csr + (size_t)dS * CAP;
    int jj = lane & 15;
    for (int j = jj; j < mdeg; j += 16) {
        int s = rowp[j];
        float nm = rsqrtf((float)cnt[s]) * did;
        bool ok = j < degS;
        metaL[wv][sub][j] = make_float2(ok ? nm : 0.f, __int_as_float(ok ? s : 0));
    }

    int slot = (lane >> 2) & 3, r = lane & 3;
    const _Float16* plane = (const _Float16*)h + (size_t)sl * NN * 32;
    float acc[8];
#pragma unroll
    for (int k = 0; k < 8; ++k) acc[k] = 0.f;
    int trips = (mdeg + 3) >> 2;
    const float2* mrow = &metaL[wv][sub][0];
    for (int t = 0; t < trips; ++t) {
        float2 ms = mrow[t * 4 + slot];
        int sj = __float_as_int(ms.y);
        half8 hv = *(const half8*)(plane + (((sj << 2) + r) << 3));
        fma_h8v(hv, ms.x, acc);
    }
#pragma unroll
    for (int k = 0; k < 8; ++k) {
        acc[k] += __shfl_xor(acc[k], 4);
        acc[k] += __shfl_xor(acc[k], 8);
    }
    if ((lane & 12) == 0) {
        int cb = sl * 32 + r * 8;
        __half2 ho[4];
#pragma unroll
        for (int k = 0; k < 4; ++k) {
            float oa = acc[2 * k]     + bias[cb + 2 * k];
            float ob = acc[2 * k + 1] + bias[cb + 2 * k + 1];
            ho[k] = __floats2half2_rn(oa, ob);
        }
        uint4 u;
        __builtin_memcpy(&u, &ho[0], 16);
        *(uint4*)&z[(size_t)dS * 64 + cb] = u;   // decode reuses z soon: keep in L2
    }
}

// ---------------- link decode (fp16 z, fp32 dot) ----------------

__global__ __launch_bounds__(256) void k_decode(const __half* __restrict__ z,
                                                const int* __restrict__ eli,
                                                float* __restrict__ outp) {
    int lane = threadIdx.x & 63, wv = threadIdx.x >> 6;
    int g = lane >> 4, r = lane & 15;
    int idx = (blockIdx.x * 4 + wv) * 4 + g;
    if (idx >= NLBL) return;
    int a = eli[idx], b = eli[NLBL + idx];
    uint2 ua = *(const uint2*)&z[(size_t)a * 64 + r * 4];
    uint2 ub = *(const uint2*)&z[(size_t)b * 64 + r * 4];
    float2 a0 = __half22float2(*(__half2*)&ua.x);
    float2 a1 = __half22float2(*(__half2*)&ua.y);
    float2 b0 = __half22float2(*(__half2*)&ub.x);
    float2 b1 = __half22float2(*(__half2*)&ub.y);
    float v = a0.x * b0.x + a0.y * b0.y + a1.x * b1.x + a1.y * b1.y;
#pragma unroll
    for (int off = 8; off; off >>= 1) v += __shfl_xor(v, off);
    if (r == 0) outp[idx] = v;
}

// ---------------- launch ----------------

extern "C" void kernel_launch(void* const* d_in, const int* in_sizes, int n_in,
                              void* d_out, int out_size, void* d_ws, size_t ws_size,
                              hipStream_t stream) {
    const float* x   = (const float*)d_in[0];
    const int*   ei  = (const int*)d_in[1];
    const int*   eli = (const int*)d_in[2];
    const float* W1 = (const float*)d_in[3];
    const float* a1s = (const float*)d_in[4];
    const float* a1d = (const float*)d_in[5];
    const float* b1 = (const float*)d_in[6];
    const float* W2 = (const float*)d_in[7];
    const float* a2s = (const float*)d_in[8];
    const float* a2d = (const float*)d_in[9];
    const float* b2 = (const float*)d_in[10];
    const float* W3 = (const float*)d_in[11];
    const float* a3s = (const float*)d_in[12];
    const float* a3d = (const float*)d_in[13];
    const float* b3 = (const float*)d_in[14];
    const float* W4 = (const float*)d_in[15];
    const float* b4 = (const float*)d_in[16];
    float* outp = (float*)d_out;

    char* p = (char*)d_ws;
    auto alloc = [&](size_t bytes) -> char* {
        char* r = p;
        p += (bytes + 255) & ~(size_t)255;
        return r;
    };
    int*    cnt  = (int*)alloc((size_t)NN * 4);
    u16*    csr  = (u16*)alloc((size_t)NN * CAP * 2);
    int*    gcnt = (int*)alloc((size_t)NBK * 4);
    float*  asvA = (float*)alloc((size_t)NN * 4);
    float*  advA = (float*)alloc((size_t)NN * 4);
    float*  asvB = (float*)alloc((size_t)NN * 4);
    float*  advB = (float*)alloc((size_t)NN * 4);
    float2* msv  = (float2*)alloc((size_t)NN * 8);
    __half* G    = (__half*)alloc((size_t)NN * 128 * 2);   // gather planes [4][NN][32]
    __half* B    = (__half*)alloc((size_t)NN * 128 * 2);   // agg output, row-major 256B rows
    __half* zf   = (__half*)alloc((size_t)NN * 64 * 2);    // gcn output
    half8*  Wf1  = (half8*)alloc(2048 * 16);
    half8*  Wf2  = (half8*)alloc(2048 * 16);
    half8*  Wf3  = (half8*)alloc(2048 * 16);
    half8*  Wf4  = (half8*)alloc(1024 * 16);
    unsigned* bins = (unsigned*)alloc((size_t)NBK * CAPB * 4);

    const int gG1   = GBIN + 782;          // bin blocks + gemm1 blocks
    const int gGemm = (NN + 15) / 16;      // 3125 one-wave blocks
    const int gSc   = (NN + 3) / 4;        // 12500 score blocks
    const int gAgg  = (NN / 16) * 4;       // 12500: 3125 dst-groups x 4 col-slices
    const int gGcn  = (NN / 16) * 2;       // 6250:  3125 dst-groups x 2 col-slices
    const int gDec  = (NLBL + 15) / 16;

    k_pre<<<29, 256, 0, stream>>>(W1, W2, W3, W4, Wf1, Wf2, Wf3, Wf4, gcnt);
    k_bin_gemm1<<<gG1, 256, 0, stream>>>(ei, gcnt, bins, x, Wf1, G, a1s, a1d, asvA, advA);
    k_build<<<NBK, 256, 0, stream>>>(bins, gcnt, cnt, csr);

    // layer 1 agg + layer 2 gemm
    k_scores<<<gSc, 256, 0, stream>>>(cnt, csr, asvA, advA, msv);
    k_gat_agg_sl<<<gAgg, 256, 0, stream>>>(G, cnt, csr, asvA, advA, msv, b1, B);
    k_gemm64<128, true><<<gGemm, 64, 0, stream>>>(B, Wf2, G, a2s, a2d, asvB, advB);

    // layer 2 agg + layer 3 gemm
    k_scores<<<gSc, 256, 0, stream>>>(cnt, csr, asvB, advB, msv);
    k_gat_agg_sl<<<gAgg, 256, 0, stream>>>(G, cnt, csr, asvB, advB, msv, b2, B);
    k_gemm64<128, true><<<gGemm, 64, 0, stream>>>(B, Wf3, G, a3s, a3d, asvA, advA);

    // layer 3 agg + layer 4 gemm (64-col, planes [2][NN][32] into G)
    k_scores<<<gSc, 256, 0, stream>>>(cnt, csr, asvA, advA, msv);
    k_gat_agg_sl<<<gAgg, 256, 0, stream>>>(G, cnt, csr, asvA, advA, msv, b3, B);
    k_gemm64<64, false><<<gGemm, 64, 0, stream>>>(B, Wf4, G, nullptr, nullptr, nullptr, nullptr);

    k_gcn_agg_sl<<<gGcn, 256, 0, stream>>>(G, cnt, csr, b4, zf);

    k_decode<<<gDec, 256, 0, stream>>>(zf, eli, outp);
}

// Round 6
// 403.508 us; speedup vs baseline: 1.3516x; 1.1320x over previous
//
#include <hip/hip_runtime.h>
#include <hip/hip_fp16.h>
#include <math.h>

#define NN   50000
#define NE   1600000
#define NLBL 200000
#define CAP  80          // max in-degree+1; Poisson(32): P(deg>=80) ~ 1e-12/node
#define NEG  0.2f
#define NBK  196         // ceil(50000/256) dst buckets of 256 nodes
#define CAPB 8800        // bucket capacity: Poisson(8163) + 7 sigma
#define CHK  4096        // edges per bin block
#define GBIN 391         // (NE+CHK-1)/CHK

typedef unsigned short u16;
typedef _Float16 half8 __attribute__((ext_vector_type(8)));
typedef float floatx4 __attribute__((ext_vector_type(4)));

// ---------------- bin phase (device fn): binned counting sort, coalesced writes ----------------
// stage word: [31:24]=bucket, [23:16]=dst&255, [15:0]=src

__device__ void ph_bin(int blk, const int* __restrict__ ei,
                       int* __restrict__ gcnt, unsigned* __restrict__ bins) {
    __shared__ int cntL[NBK];
    __shared__ int offL[NBK];
    __shared__ int curL[NBK];
    __shared__ int curG[NBK];
    __shared__ unsigned stage[CHK];   // 16 KB
    const int tid = threadIdx.x;
    const int e0 = blk * CHK + tid * 16;
    const bool act = (e0 + 15) < NE;

    unsigned pk[16];
    int bb[16];
    if (act) {
#pragma unroll
        for (int g = 0; g < 4; ++g) {
            int4 s4 = *(const int4*)&ei[e0 + g * 4];
            int4 d4 = *(const int4*)&ei[NE + e0 + g * 4];
            int sa[4] = {s4.x, s4.y, s4.z, s4.w};
            int da[4] = {d4.x, d4.y, d4.z, d4.w};
#pragma unroll
            for (int k = 0; k < 4; ++k) {
                int idx = g * 4 + k;
                bb[idx] = da[k] >> 8;
                pk[idx] = (unsigned)sa[k] | ((unsigned)(da[k] & 255) << 16)
                        | ((unsigned)bb[idx] << 24);
            }
        }
    }
    for (int i = tid; i < NBK; i += 256) cntL[i] = 0;
    __syncthreads();
    if (act) {
#pragma unroll
        for (int k = 0; k < 16; ++k) atomicAdd(&cntL[bb[k]], 1);
    }
    __syncthreads();
    if (tid < NBK) {
        int acc = 0;
        for (int i = 0; i < tid; ++i) acc += cntL[i];
        offL[tid] = acc;
        curL[tid] = acc;
    }
    __syncthreads();
    for (int i = tid; i < NBK; i += 256) curG[i] = atomicAdd(&gcnt[i], cntL[i]);
    __syncthreads();
    if (act) {
#pragma unroll
        for (int k = 0; k < 16; ++k) {
            int pos = atomicAdd(&curL[bb[k]], 1);
            stage[pos] = pk[k];
        }
    }
    __syncthreads();
    const int tot = offL[NBK - 1] + cntL[NBK - 1];
    for (int j = tid; j < tot; j += 256) {
        unsigned v = stage[j];
        int b = v >> 24;
        int lr = j - offL[b];
        bins[(size_t)b * CAPB + curG[b] + lr] = v & 0x00FFFFFFu;
    }
}

__global__ __launch_bounds__(256) void k_build(const unsigned* __restrict__ bins,
                                               const int* __restrict__ gcnt,
                                               int* __restrict__ cnt,
                                               u16* __restrict__ csr) {
    __shared__ u16 rows[256 * CAP];   // 40 KB
    __shared__ int cur[256];
    const int b = blockIdx.x, tid = threadIdx.x;
    const int d0 = b << 8;
    const int nd = min(256, NN - d0);
    if (tid < nd) { cur[tid] = 1; rows[tid * CAP] = (u16)(d0 + tid); }  // self-loop slot 0
    __syncthreads();
    const int n = gcnt[b];
    for (int i = tid; i < n; i += 256) {
        unsigned v = bins[(size_t)b * CAPB + i];
        int s = v & 0xFFFF, dl = (v >> 16) & 0xFF;
        int pos = atomicAdd(&cur[dl], 1);
        if (pos < CAP) rows[dl * CAP + pos] = (u16)s;
    }
    __syncthreads();
    const unsigned* rw = (const unsigned*)rows;
    unsigned* cw = (unsigned*)(csr + (size_t)d0 * CAP);
    const int tot = nd * (CAP / 2);
    for (int i = tid; i < tot; i += 256) cw[i] = rw[i];
    if (tid < nd) cnt[d0 + tid] = cur[tid];
}

// ---------------- W -> fp16 fragment layout + gcnt zero ----------------

__global__ __launch_bounds__(256) void k_pre(const float* __restrict__ W1f,
                                             const float* __restrict__ W2f,
                                             const float* __restrict__ W3f,
                                             const float* __restrict__ W4f,
                                             half8* __restrict__ Wf1,
                                             half8* __restrict__ Wf2,
                                             half8* __restrict__ Wf3,
                                             half8* __restrict__ Wf4,
                                             int* __restrict__ gcnt) {
    if (blockIdx.x == 28) {       // folded zero
        int i = threadIdx.x;
        if (i < NBK) gcnt[i] = 0;
        return;
    }
    int e = blockIdx.x * 256 + threadIdx.x;
    const float* W;
    half8* Wf;
    int nout, le;
    if (e < 2048)      { W = W1f; Wf = Wf1; nout = 128; le = e; }
    else if (e < 4096) { W = W2f; Wf = Wf2; nout = 128; le = e - 2048; }
    else if (e < 6144) { W = W3f; Wf = Wf3; nout = 128; le = e - 4096; }
    else               { W = W4f; Wf = Wf4; nout = 64;  le = e - 6144; }
    int c = le >> 8, rem = le & 255, ks = rem >> 6, lane = rem & 63;
    int n = lane & 15, quad = lane >> 4;
    int col = c * 16 + n, k0 = ks * 32 + quad * 8;
    half8 v;
#pragma unroll
    for (int j = 0; j < 8; ++j) v[j] = (_Float16)W[(size_t)(k0 + j) * nout + col];
    Wf[le] = v;
}

// ---------------- MFMA fp16 GEMM tile: 16 rows; row-major input, PLANE output ----------------
// mfma(argA=W-frag, argB=A-frag): D[row=quad*4+reg -> w_col][col=lane&15 -> a_row].
// Output C in column-plane layout: plane p = col>>5 (32 cols, 64B rows), C[((p*NN)+row)*32 + col&31].

template <int NOUT, bool ATTN, typename TA>
__device__ __forceinline__ void gemm_tile(int gt, int lane,
                                          const TA* __restrict__ A,
                                          const half8* __restrict__ Wf,
                                          __half* __restrict__ C,
                                          const float* __restrict__ a_s,
                                          const float* __restrict__ a_d,
                                          float* __restrict__ asv,
                                          float* __restrict__ adv) {
    constexpr int CT = NOUT / 16;
    const int n = lane & 15, quad = lane >> 4;
    if (gt * 16 >= NN) return;            // 3125 tiles cover 50000 rows exactly
    const int row = gt * 16 + n;

    half8 a[4];
#pragma unroll
    for (int ks = 0; ks < 4; ++ks) {
        int c128 = ks * 32 + quad * 8;
        if constexpr (sizeof(TA) == 2) {
            a[ks] = *(const half8*)((const _Float16*)A + (size_t)row * 128 + c128);
        } else {
            const float* Ap = (const float*)A + (size_t)row * 128 + c128;
            float4 f0 = *(const float4*)Ap;
            float4 f1 = *(const float4*)(Ap + 4);
            half8 v;
            v[0] = (_Float16)f0.x; v[1] = (_Float16)f0.y; v[2] = (_Float16)f0.z; v[3] = (_Float16)f0.w;
            v[4] = (_Float16)f1.x; v[5] = (_Float16)f1.y; v[6] = (_Float16)f1.z; v[7] = (_Float16)f1.w;
            a[ks] = v;
        }
    }

    floatx4 acc[CT];
#pragma unroll
    for (int c = 0; c < CT; ++c) acc[c] = (floatx4){0.f, 0.f, 0.f, 0.f};
#pragma unroll
    for (int c = 0; c < CT; ++c) {
#pragma unroll
        for (int ks = 0; ks < 4; ++ks) {
            half8 b = Wf[(c * 4 + ks) * 64 + lane];
            acc[c] = __builtin_amdgcn_mfma_f32_16x16x32_f16(b, a[ks], acc[c], 0, 0, 0);
        }
    }

#pragma unroll
    for (int c = 0; c < CT; ++c) {
        __half2 h0 = __floats2half2_rn(acc[c][0], acc[c][1]);
        __half2 h1 = __floats2half2_rn(acc[c][2], acc[c][3]);
        uint2 u;
        __builtin_memcpy(&u.x, &h0, 4);
        __builtin_memcpy(&u.y, &h1, 4);
        int col = c * 16 + quad * 4;
        int pl = col >> 5, off = col & 31;
        *(uint2*)&C[((size_t)pl * NN + row) * 32 + off] = u;
    }

    if (ATTN) {   // fused attn dots (fp32 from acc); reduce across quads
        float ps = 0.f, pd = 0.f;
#pragma unroll
        for (int c = 0; c < CT; ++c) {
#pragma unroll
            for (int reg = 0; reg < 4; ++reg) {
                float w = acc[c][reg];
                ps = fmaf(w, a_s[c * 16 + quad * 4 + reg], ps);
                pd = fmaf(w, a_d[c * 16 + quad * 4 + reg], pd);
            }
        }
        ps += __shfl_xor(ps, 16); ps += __shfl_xor(ps, 32);
        pd += __shfl_xor(pd, 16); pd += __shfl_xor(pd, 32);
        if (quad == 0) { asv[row] = ps; adv[row] = pd; }
    }
}

// fused: blocks [0,GBIN) bin edges; blocks [GBIN, GBIN+782) run layer-1 GEMM (fp32 x input).
__global__ __launch_bounds__(256) void k_bin_gemm1(const int* __restrict__ ei,
                                                   int* __restrict__ gcnt,
                                                   unsigned* __restrict__ bins,
                                                   const float* __restrict__ x,
                                                   const half8* __restrict__ Wf1,
                                                   __half* __restrict__ G,
                                                   const float* __restrict__ a_s,
                                                   const float* __restrict__ a_d,
                                                   float* __restrict__ asv,
                                                   float* __restrict__ adv) {
    if (blockIdx.x < GBIN) { ph_bin(blockIdx.x, ei, gcnt, bins); return; }
    int gt = (blockIdx.x - GBIN) * 4 + (threadIdx.x >> 6);
    gemm_tile<128, true, float>(gt, threadIdx.x & 63, x, Wf1, G, a_s, a_d, asv, adv);
}

// standalone 64-thread GEMM kernels: 3125 one-wave blocks for load balance
template <int NOUT, bool ATTN>
__global__ __launch_bounds__(64) void k_gemm64(const __half* __restrict__ A,
                                               const half8* __restrict__ Wf,
                                               __half* __restrict__ C,
                                               const float* __restrict__ a_s,
                                               const float* __restrict__ a_d,
                                               float* __restrict__ asv,
                                               float* __restrict__ adv) {
    gemm_tile<NOUT, ATTN, __half>(blockIdx.x, threadIdx.x & 63, A, Wf, C,
                                  a_s, a_d, asv, adv);
}

// fma 8 halves scaled by al into acc[0..7] (v_fma_mix-friendly form)
__device__ __forceinline__ void fma_h8v(half8 h, float al, float* acc) {
#pragma unroll
    for (int k = 0; k < 8; ++k) acc[k] = fmaf(al, (float)h[k], acc[k]);
}

// ---------------- XCD-sliced GAT aggregation, v3: register meta + shuffle ----------------
// slice = blockIdx.x & 3 (round-robin dispatch -> plane pinned to 2 XCDs; FETCH floor
// ~47MB, measured r3/r4). Wave = 4 dsts x 4 slots x 4 lanes x 8 cols.
// v3 fixes r4's latency bound: no LDS meta (alpha lives in regs of the 16 alpha
// lanes, consumers bpermute it), softmax fused in (k_scores deleted), gather
// chunk-unrolled 4-deep so 4 independent 16B loads are in flight per wave.

__global__ __launch_bounds__(256) void k_gat_agg_sl(const __half* __restrict__ h,  // [4][NN][32]
                                                    const int* __restrict__ cnt,
                                                    const u16* __restrict__ csr,
                                                    const float* __restrict__ asv,
                                                    const float* __restrict__ adv,
                                                    const float* __restrict__ bias,
                                                    __half* __restrict__ out) {
    int lane = threadIdx.x & 63, wv = threadIdx.x >> 6;
    int sl = blockIdx.x & 3;
    int d0 = (blockIdx.x >> 2) * 16 + wv * 4;   // 3125 groups x 16 = NN exactly
    int sub = lane >> 4;
    int dS = d0 + sub;
    int degS = cnt[dS]; if (degS > CAP) degS = CAP;
    int jj = lane & 15;
    const u16* rowp = csr + (size_t)dS * CAP;

    // ---- all 5 chunk srcs, unconditional (CAP-padded row) then masked ----
    int s0 = rowp[jj];
    int s1 = rowp[jj + 16];
    int s2 = rowp[jj + 32];
    int s3 = rowp[jj + 48];
    int s4 = rowp[jj + 64];
    bool v0 = jj < degS, v1 = jj + 16 < degS, v2 = jj + 32 < degS,
         v3 = jj + 48 < degS, v4 = jj + 64 < degS;
    s0 = v0 ? s0 : 0; s1 = v1 ? s1 : 0; s2 = v2 ? s2 : 0;
    s3 = v3 ? s3 : 0; s4 = v4 ? s4 : 0;

    // batched asv gathers
    float y0 = asv[s0], y1 = asv[s1], y2 = asv[s2], y3 = asv[s3], y4 = asv[s4];
    const float advd = adv[dS];

    // leaky-relu scores; invalid -> -inf (exp gives exact 0)
    float t0 = y0 + advd, t1 = y1 + advd, t2 = y2 + advd, t3 = y3 + advd, t4 = y4 + advd;
    float e0 = v0 ? ((t0 >= 0.f) ? t0 : NEG * t0) : -INFINITY;
    float e1 = v1 ? ((t1 >= 0.f) ? t1 : NEG * t1) : -INFINITY;
    float e2 = v2 ? ((t2 >= 0.f) ? t2 : NEG * t2) : -INFINITY;
    float e3 = v3 ? ((t3 >= 0.f) ? t3 : NEG * t3) : -INFINITY;
    float e4 = v4 ? ((t4 >= 0.f) ? t4 : NEG * t4) : -INFINITY;

    // softmax over the 16-lane sub group (xor 1,2,4,8 stays in group)
    float m = fmaxf(fmaxf(fmaxf(e0, e1), fmaxf(e2, e3)), e4);
    m = fmaxf(m, __shfl_xor(m, 1));
    m = fmaxf(m, __shfl_xor(m, 2));
    m = fmaxf(m, __shfl_xor(m, 4));
    m = fmaxf(m, __shfl_xor(m, 8));
    float p0 = __expf(e0 - m), p1 = __expf(e1 - m), p2 = __expf(e2 - m),
          p3 = __expf(e3 - m), p4 = __expf(e4 - m);
    float s = p0 + p1 + p2 + p3 + p4;
    s += __shfl_xor(s, 1);
    s += __shfl_xor(s, 2);
    s += __shfl_xor(s, 4);
    s += __shfl_xor(s, 8);
    float inv = 1.f / s;
    float al0 = p0 * inv, al1 = p1 * inv, al2 = p2 * inv, al3 = p3 * inv, al4 = p4 * inv;

    // wave-max degree -> uniform chunk count
    int mdeg = degS;
    mdeg = max(mdeg, __shfl_xor(mdeg, 16));
    mdeg = max(mdeg, __shfl_xor(mdeg, 32));

    // ---- gather: 4 slots x 4 lanes x 8 cols, chunk = 16 edges, 4 loads in flight ----
    int slot = (lane >> 2) & 3, r = lane & 3;
    const _Float16* plane = (const _Float16*)h + (size_t)sl * NN * 32 + r * 8;
    float acc[8];
#pragma unroll
    for (int k = 0; k < 8; ++k) acc[k] = 0.f;
    int sbase = lane & 0x30;

    auto chunk = [&](float alK, int sK) {
        float aa[4]; int ss[4];
#pragma unroll
        for (int t2 = 0; t2 < 4; ++t2) {
            int srcl = sbase | (t2 << 2) | slot;
            aa[t2] = __shfl(alK, srcl);
            ss[t2] = __shfl(sK, srcl);
        }
        half8 hv[4];
#pragma unroll
        for (int t2 = 0; t2 < 4; ++t2) hv[t2] = *(const half8*)(plane + (size_t)ss[t2] * 32);
#pragma unroll
        for (int t2 = 0; t2 < 4; ++t2) fma_h8v(hv[t2], aa[t2], acc);
    };
    chunk(al0, s0);
    if (mdeg > 16) chunk(al1, s1);
    if (mdeg > 32) chunk(al2, s2);
    if (mdeg > 48) chunk(al3, s3);
    if (mdeg > 64) chunk(al4, s4);

#pragma unroll
    for (int k = 0; k < 8; ++k) {
        acc[k] += __shfl_xor(acc[k], 4);
        acc[k] += __shfl_xor(acc[k], 8);
    }
    if ((lane & 12) == 0) {    // slot 0: 4 lanes cover this slice's 32 cols
        int cb = sl * 32 + r * 8;
        __half2 ho[4];
#pragma unroll
        for (int k = 0; k < 4; ++k) {
            float oa = fmaxf(acc[2 * k]     + bias[cb + 2 * k],     0.f);
            float ob = fmaxf(acc[2 * k + 1] + bias[cb + 2 * k + 1], 0.f);
            ho[k] = __floats2half2_rn(oa, ob);
        }
        uint4 u;
        __builtin_memcpy(&u, &ho[0], 16);
        *(uint4*)&out[(size_t)dS * 128 + cb] = u;   // row-major for the next GEMM
    }
}

// ---------------- XCD-sliced GCN aggregation, v3 (2 planes of 32 cols) ----------------

__global__ __launch_bounds__(256) void k_gcn_agg_sl(const __half* __restrict__ h,  // [2][NN][32]
                                                    const int* __restrict__ cnt,
                                                    const u16* __restrict__ csr,
                                                    const float* __restrict__ bias,
                                                    __half* __restrict__ z) {
    int lane = threadIdx.x & 63, wv = threadIdx.x >> 6;
    int sl = blockIdx.x & 1;
    int d0 = (blockIdx.x >> 1) * 16 + wv * 4;   // 3125 groups x 16 = NN exactly
    int sub = lane >> 4;
    int dS = d0 + sub;
    int degc = cnt[dS];
    int degS = degc > CAP ? CAP : degc;
    int jj = lane & 15;
    const u16* rowp = csr + (size_t)dS * CAP;

    int s0 = rowp[jj];
    int s1 = rowp[jj + 16];
    int s2 = rowp[jj + 32];
    int s3 = rowp[jj + 48];
    int s4 = rowp[jj + 64];
    bool v0 = jj < degS, v1 = jj + 16 < degS, v2 = jj + 32 < degS,
         v3 = jj + 48 < degS, v4 = jj + 64 < degS;
    s0 = v0 ? s0 : 0; s1 = v1 ? s1 : 0; s2 = v2 ? s2 : 0;
    s3 = v3 ? s3 : 0; s4 = v4 ? s4 : 0;

    float c0 = (float)cnt[s0], c1 = (float)cnt[s1], c2 = (float)cnt[s2],
          c3 = (float)cnt[s3], c4 = (float)cnt[s4];
    float did = rsqrtf((float)degc);
    float al0 = v0 ? rsqrtf(c0) * did : 0.f;
    float al1 = v1 ? rsqrtf(c1) * did : 0.f;
    float al2 = v2 ? rsqrtf(c2) * did : 0.f;
    float al3 = v3 ? rsqrtf(c3) * did : 0.f;
    float al4 = v4 ? rsqrtf(c4) * did : 0.f;

    int mdeg = degS;
    mdeg = max(mdeg, __shfl_xor(mdeg, 16));
    mdeg = max(mdeg, __shfl_xor(mdeg, 32));

    int slot = (lane >> 2) & 3, r = lane & 3;
    const _Float16* plane = (const _Float16*)h + (size_t)sl * NN * 32 + r * 8;
    float acc[8];
#pragma unroll
    for (int k = 0; k < 8; ++k) acc[k] = 0.f;
    int sbase = lane & 0x30;

    auto chunk = [&](float alK, int sK) {
        float aa[4]; int ss[4];
#pragma unroll
        for (int t2 = 0; t2 < 4; ++t2) {
            int srcl = sbase | (t2 << 2) | slot;
            aa[t2] = __shfl(alK, srcl);
            ss[t2] = __shfl(sK, srcl);
        }
        half8 hv[4];
#pragma unroll
        for (int t2 = 0; t2 < 4; ++t2) hv[t2] = *(const half8*)(plane + (size_t)ss[t2] * 32);
#pragma unroll
        for (int t2 = 0; t2 < 4; ++t2) fma_h8v(hv[t2], aa[t2], acc);
    };
    chunk(al0, s0);
    if (mdeg > 16) chunk(al1, s1);
    if (mdeg > 32) chunk(al2, s2);
    if (mdeg > 48) chunk(al3, s3);
    if (mdeg > 64) chunk(al4, s4);

#pragma unroll
    for (int k = 0; k < 8; ++k) {
        acc[k] += __shfl_xor(acc[k], 4);
        acc[k] += __shfl_xor(acc[k], 8);
    }
    if ((lane & 12) == 0) {
        int cb = sl * 32 + r * 8;
        __half2 ho[4];
#pragma unroll
        for (int k = 0; k < 4; ++k) {
            float oa = acc[2 * k]     + bias[cb + 2 * k];
            float ob = acc[2 * k + 1] + bias[cb + 2 * k + 1];
            ho[k] = __floats2half2_rn(oa, ob);
        }
        uint4 u;
        __builtin_memcpy(&u, &ho[0], 16);
        *(uint4*)&z[(size_t)dS * 64 + cb] = u;   // decode reuses z soon: keep in L2
    }
}

// ---------------- link decode (fp16 z, fp32 dot) ----------------

__global__ __launch_bounds__(256) void k_decode(const __half* __restrict__ z,
                                                const int* __restrict__ eli,
                                                float* __restrict__ outp) {
    int lane = threadIdx.x & 63, wv = threadIdx.x >> 6;
    int g = lane >> 4, r = lane & 15;
    int idx = (blockIdx.x * 4 + wv) * 4 + g;
    if (idx >= NLBL) return;
    int a = eli[idx], b = eli[NLBL + idx];
    uint2 ua = *(const uint2*)&z[(size_t)a * 64 + r * 4];
    uint2 ub = *(const uint2*)&z[(size_t)b * 64 + r * 4];
    float2 a0 = __half22float2(*(__half2*)&ua.x);
    float2 a1 = __half22float2(*(__half2*)&ua.y);
    float2 b0 = __half22float2(*(__half2*)&ub.x);
    float2 b1 = __half22float2(*(__half2*)&ub.y);
    float v = a0.x * b0.x + a0.y * b0.y + a1.x * b1.x + a1.y * b1.y;
#pragma unroll
    for (int off = 8; off; off >>= 1) v += __shfl_xor(v, off);
    if (r == 0) outp[idx] = v;
}

// ---------------- launch ----------------

extern "C" void kernel_launch(void* const* d_in, const int* in_sizes, int n_in,
                              void* d_out, int out_size, void* d_ws, size_t ws_size,
                              hipStream_t stream) {
    const float* x   = (const float*)d_in[0];
    const int*   ei  = (const int*)d_in[1];
    const int*   eli = (const int*)d_in[2];
    const float* W1 = (const float*)d_in[3];
    const float* a1s = (const float*)d_in[4];
    const float* a1d = (const float*)d_in[5];
    const float* b1 = (const float*)d_in[6];
    const float* W2 = (const float*)d_in[7];
    const float* a2s = (const float*)d_in[8];
    const float* a2d = (const float*)d_in[9];
    const float* b2 = (const float*)d_in[10];
    const float* W3 = (const float*)d_in[11];
    const float* a3s = (const float*)d_in[12];
    const float* a3d = (const float*)d_in[13];
    const float* b3 = (const float*)d_in[14];
    const float* W4 = (const float*)d_in[15];
    const float* b4 = (const float*)d_in[16];
    float* outp = (float*)d_out;

    char* p = (char*)d_ws;
    auto alloc = [&](size_t bytes) -> char* {
        char* r = p;
        p += (bytes + 255) & ~(size_t)255;
        return r;
    };
    int*    cnt  = (int*)alloc((size_t)NN * 4);
    u16*    csr  = (u16*)alloc((size_t)NN * CAP * 2);
    int*    gcnt = (int*)alloc((size_t)NBK * 4);
    float*  asvA = (float*)alloc((size_t)NN * 4);
    float*  advA = (float*)alloc((size_t)NN * 4);
    float*  asvB = (float*)alloc((size_t)NN * 4);
    float*  advB = (float*)alloc((size_t)NN * 4);
    __half* G    = (__half*)alloc((size_t)NN * 128 * 2);   // gather planes [4][NN][32]
    __half* B    = (__half*)alloc((size_t)NN * 128 * 2);   // agg output, row-major 256B rows
    __half* zf   = (__half*)alloc((size_t)NN * 64 * 2);    // gcn output
    half8*  Wf1  = (half8*)alloc(2048 * 16);
    half8*  Wf2  = (half8*)alloc(2048 * 16);
    half8*  Wf3  = (half8*)alloc(2048 * 16);
    half8*  Wf4  = (half8*)alloc(1024 * 16);
    unsigned* bins = (unsigned*)alloc((size_t)NBK * CAPB * 4);

    const int gG1   = GBIN + 782;          // bin blocks + gemm1 blocks
    const int gGemm = (NN + 15) / 16;      // 3125 one-wave blocks
    const int gAgg  = (NN / 16) * 4;       // 12500: 3125 dst-groups x 4 col-slices
    const int gGcn  = (NN / 16) * 2;       // 6250:  3125 dst-groups x 2 col-slices
    const int gDec  = (NLBL + 15) / 16;

    k_pre<<<29, 256, 0, stream>>>(W1, W2, W3, W4, Wf1, Wf2, Wf3, Wf4, gcnt);
    k_bin_gemm1<<<gG1, 256, 0, stream>>>(ei, gcnt, bins, x, Wf1, G, a1s, a1d, asvA, advA);
    k_build<<<NBK, 256, 0, stream>>>(bins, gcnt, cnt, csr);

    // layer 1 agg + layer 2 gemm
    k_gat_agg_sl<<<gAgg, 256, 0, stream>>>(G, cnt, csr, asvA, advA, b1, B);
    k_gemm64<128, true><<<gGemm, 64, 0, stream>>>(B, Wf2, G, a2s, a2d, asvB, advB);

    // layer 2 agg + layer 3 gemm
    k_gat_agg_sl<<<gAgg, 256, 0, stream>>>(G, cnt, csr, asvB, advB, b2, B);
    k_gemm64<128, true><<<gGemm, 64, 0, stream>>>(B, Wf3, G, a3s, a3d, asvA, advA);

    // layer 3 agg + layer 4 gemm (64-col, planes [2][NN][32] into G)
    k_gat_agg_sl<<<gAgg, 256, 0, stream>>>(G, cnt, csr, asvA, advA, b3, B);
    k_gemm64<64, false><<<gGemm, 64, 0, stream>>>(B, Wf4, G, nullptr, nullptr, nullptr, nullptr);

    k_gcn_agg_sl<<<gGcn, 256, 0, stream>>>(G, cnt, csr, b4, zf);

    k_decode<<<gDec, 256, 0, stream>>>(zf, eli, outp);
}